// Round 1
// baseline (2727.929 us; speedup 1.0000x reference)
//
#include <hip/hip_runtime.h>
#include <stdint.h>

// RNG scheme: 1 = jax_threefry_partitionable=True (modern default, bits = o0^o1 of (0, idx))
//             0 = legacy split-half counter scheme
#ifndef RNG_PARTITIONABLE
#define RNG_PARTITIONABLE 1
#endif

static constexpr int NB = 32, NH = 16, ND = 64, NS = 1024;
static constexpr int SZ = 262144;
static constexpr uint32_t HALFN = 67108864u; // NB*NH*SZ/2

__device__ __forceinline__ uint32_t rotl32(uint32_t x, int r) { return (x << r) | (x >> (32 - r)); }

// Threefry-2x32-20 with key (0, 42): ks = [0, 42, 0x1BD11BDA^42 = 0x1BD11BF0]
__device__ __forceinline__ void tf2x32(uint32_t x0, uint32_t x1, uint32_t& o0, uint32_t& o1) {
  const uint32_t K1 = 42u, K2 = 0x1BD11BF0u;
  x1 += K1;
#define TFR(r) { x0 += x1; x1 = rotl32(x1, (r)); x1 ^= x0; }
  TFR(13) TFR(15) TFR(26) TFR(6)
  x0 += K1; x1 += K2 + 1u;
  TFR(17) TFR(29) TFR(16) TFR(24)
  x0 += K2; x1 += 2u;
  TFR(13) TFR(15) TFR(26) TFR(6)
  /* x0 += 0 */ x1 += K1 + 3u;
  TFR(17) TFR(29) TFR(16) TFR(24)
  x0 += K1; x1 += K2 + 4u;
  TFR(13) TFR(15) TFR(26) TFR(6)
  x0 += K2; x1 += 5u;
#undef TFR
  o0 = x0; o1 = x1;
}

// gumbel(b,h,s) exactly as jax: u = max(1e-12, bitcast((bits>>9)|0x3f800000)-1 + 1e-12); -log(-log(u))
__device__ __forceinline__ float gumbel_of(uint32_t row, uint32_t s) {
  uint32_t p = (row << 18) | s;   // flat index into (B,H,SIZE)
  uint32_t bits;
#if RNG_PARTITIONABLE
  uint32_t o0, o1; tf2x32(0u, p, o0, o1); bits = o0 ^ o1;
#else
  uint32_t o0, o1;
  if (p < HALFN) { tf2x32(p, p + HALFN, o0, o1); bits = o0; }
  else           { tf2x32(p - HALFN, p, o0, o1); bits = o1; }
#endif
  float f = __uint_as_float((bits >> 9) | 0x3f800000u) - 1.0f;
  float u = fmaxf(1e-12f, f + 1e-12f);
  float t = -logf(u);
  return -logf(t);
}

// order-preserving float -> uint key (bigger float => bigger key)
__device__ __forceinline__ uint32_t fkey(float v) {
  uint32_t u = __float_as_uint(v);
  return (u & 0x80000000u) ? ~u : (u | 0x80000000u);
}

// logw[h][s] = logit[s][h] - logsumexp_h(logit[s][:]); also copy logit -> out, init winner=-1
__global__ void k_logw(const float* __restrict__ logit, float* __restrict__ logw,
                       float* __restrict__ outL, int* __restrict__ winner) {
  int s = blockIdx.x * blockDim.x + threadIdx.x;
  if (s >= SZ) return;
  const float4* p = (const float4*)(logit + (size_t)s * NH);
  float4 a0 = p[0], a1 = p[1], a2 = p[2], a3 = p[3];
  float x[16] = {a0.x,a0.y,a0.z,a0.w, a1.x,a1.y,a1.z,a1.w,
                 a2.x,a2.y,a2.z,a2.w, a3.x,a3.y,a3.z,a3.w};
  float m = x[0];
#pragma unroll
  for (int h = 1; h < 16; ++h) m = fmaxf(m, x[h]);
  float acc = 0.f;
#pragma unroll
  for (int h = 0; h < 16; ++h) acc += expf(x[h] - m);
  float lse = logf(acc) + m;
#pragma unroll
  for (int h = 0; h < 16; ++h) logw[(size_t)h * SZ + s] = x[h] - lse;
  float4* q = (float4*)(outL + (size_t)s * NH);
  q[0] = a0; q[1] = a1; q[2] = a2; q[3] = a3;
  int4 mone = make_int4(-1, -1, -1, -1);
  int4* w = (int4*)(winner + (size_t)s * NH);
  w[0] = mone; w[1] = mone; w[2] = mone; w[3] = mone;
}

__global__ void k_copy(const float4* __restrict__ a, float4* __restrict__ b, long n) {
  long i = (long)blockIdx.x * blockDim.x + threadIdx.x;
  long stride = (long)gridDim.x * blockDim.x;
  for (; i < n; i += stride) b[i] = a[i];
}

#define SEL_T 512
// exact top-1024 set per row via 3-level radix select on fkey; ties at exact key -> smallest s
__global__ void __launch_bounds__(SEL_T) k_select(const float* __restrict__ logw,
                                                  int* __restrict__ idx_sel) {
  const int row = blockIdx.x;
  const int h = row & 15;
  const float* lw = logw + (size_t)h * SZ;
  int* outrow = idx_sel + (size_t)row * NS;
  __shared__ uint32_t hist[4096];
  __shared__ int cand[4096];
  __shared__ int cand2[256];
  __shared__ int cand3[64];
  __shared__ int ctl[8]; // 0:nsel 1:ncand 2:T 3:ncand2 4:ncand3
  const int tid = threadIdx.x;

  for (int i = tid; i < 4096; i += SEL_T) hist[i] = 0;
  if (tid < 8) ctl[tid] = 0;
  __syncthreads();
  // pass A: 12-bit histogram
  for (int s = tid; s < SZ; s += SEL_T) {
    float v = lw[s] + gumbel_of(row, s);
    atomicAdd(&hist[fkey(v) >> 20], 1u);
  }
  __syncthreads();
  if (tid == 0) {
    uint32_t cum = 0; int T = 4095;
    for (int b = 4095; b >= 0; --b) {
      if (cum + hist[b] >= (uint32_t)NS) { T = b; break; }
      cum += hist[b];
    }
    ctl[2] = T;
  }
  __syncthreads();
  const int T0 = ctl[2];
  // pass B: accept bins > T0, collect bin == T0
  for (int s = tid; s < SZ; s += SEL_T) {
    float v = lw[s] + gumbel_of(row, s);
    uint32_t key = fkey(v);
    int b = key >> 20;
    if (b > T0)      { int p = atomicAdd(&ctl[0], 1); outrow[p] = s; }
    else if (b == T0){ int c = atomicAdd(&ctl[1], 1); if (c < 4096) cand[c] = s; }
  }
  __syncthreads();
  // level 2: next 12 bits among candidates
  const int C = min(ctl[1], 4096);
  for (int i = tid; i < 4096; i += SEL_T) hist[i] = 0;
  __syncthreads();
  for (int ci = tid; ci < C; ci += SEL_T) {
    int s = cand[ci];
    uint32_t key = fkey(lw[s] + gumbel_of(row, s));
    atomicAdd(&hist[(key >> 8) & 0xFFFu], 1u);
  }
  __syncthreads();
  if (tid == 0) {
    int need = NS - ctl[0];
    uint32_t cum = 0; int T = 4095;
    for (int b = 4095; b >= 0; --b) {
      if (cum + hist[b] >= (uint32_t)need) { T = b; break; }
      cum += hist[b];
    }
    ctl[2] = T; ctl[3] = 0;
  }
  __syncthreads();
  const int T1 = ctl[2];
  for (int ci = tid; ci < C; ci += SEL_T) {
    int s = cand[ci];
    uint32_t key = fkey(lw[s] + gumbel_of(row, s));
    int mid = (key >> 8) & 0xFFF;
    if (mid > T1)      { int p = atomicAdd(&ctl[0], 1); outrow[p] = s; }
    else if (mid == T1){ int c = atomicAdd(&ctl[3], 1); if (c < 256) cand2[c] = s; }
  }
  __syncthreads();
  // level 3: low 8 bits
  const int C2 = min(ctl[3], 256);
  if (tid < 256) hist[tid] = 0;
  __syncthreads();
  for (int ci = tid; ci < C2; ci += SEL_T) {
    int s = cand2[ci];
    uint32_t key = fkey(lw[s] + gumbel_of(row, s));
    atomicAdd(&hist[key & 0xFFu], 1u);
  }
  __syncthreads();
  if (tid == 0) {
    int need = NS - ctl[0];
    uint32_t cum = 0; int T = 255;
    for (int b = 255; b >= 0; --b) {
      if (cum + hist[b] >= (uint32_t)need) { T = b; break; }
      cum += hist[b];
    }
    ctl[2] = T; ctl[4] = 0;
  }
  __syncthreads();
  const int T2 = ctl[2];
  for (int ci = tid; ci < C2; ci += SEL_T) {
    int s = cand2[ci];
    uint32_t key = fkey(lw[s] + gumbel_of(row, s));
    int lo = key & 0xFF;
    if (lo > T2)      { int p = atomicAdd(&ctl[0], 1); outrow[p] = s; }
    else if (lo == T2){ int c = atomicAdd(&ctl[4], 1); if (c < 64) cand3[c] = s; }
  }
  __syncthreads();
  if (tid == 0) {
    int need = NS - ctl[0];
    int c3 = min(ctl[4], 64);
    for (int k = 0; k < need; ++k) {      // exact-key ties: smallest index first (top_k semantics)
      int best = 0x7fffffff, bi = 0;
      for (int j = 0; j < c3; ++j) if (cand3[j] < best) { best = cand3[j]; bi = j; }
      if (best == 0x7fffffff) best = 0;   // pathological overflow safety (should not happen)
      outrow[ctl[0] + k] = best;
      if (c3 > 0) cand3[bi] = 0x7fffffff;
    }
  }
}

// per row (b,h): scores -> softmax -> attn (ws) + lerp_k/lerp_v (d_out)
__global__ void __launch_bounds__(256) k_attn(const float* __restrict__ qin,
    const float* __restrict__ Kst, const float* __restrict__ Vst,
    const int* __restrict__ idx_sel, float* __restrict__ attn_ws,
    float* __restrict__ lerp_k, float* __restrict__ lerp_v) {
  const int row = blockIdx.x;
  const int h = row & 15;
  const int tid = threadIdx.x;
  const int lane = tid & 63, wv = tid >> 6;
  __shared__ float sc[NS];
  __shared__ float red[256];
  __shared__ float pk[4][ND], pv[4][ND];
  const int* sel = idx_sel + (size_t)row * NS;
  float qd = qin[(size_t)row * ND + lane];
  // phase 1: one wave per score
  for (int i = wv; i < NS; i += 4) {
    int idx = sel[i];
    float prod = qd * Kst[((size_t)idx * NH + h) * ND + lane];
#pragma unroll
    for (int off = 32; off; off >>= 1) prod += __shfl_xor(prod, off);
    if (lane == 0) sc[i] = prod * 0.125f;
  }
  __syncthreads();
  // softmax
  float m = -1e30f;
  for (int i = tid; i < NS; i += 256) m = fmaxf(m, sc[i]);
  red[tid] = m; __syncthreads();
  for (int w = 128; w; w >>= 1) { if (tid < w) red[tid] = fmaxf(red[tid], red[tid + w]); __syncthreads(); }
  m = red[0]; __syncthreads();
  float ssum = 0.f;
  for (int i = tid; i < NS; i += 256) { float e = expf(sc[i] - m); sc[i] = e; ssum += e; }
  red[tid] = ssum; __syncthreads();
  for (int w = 128; w; w >>= 1) { if (tid < w) red[tid] += red[tid + w]; __syncthreads(); }
  float denom = red[0]; __syncthreads();
  for (int i = tid; i < NS; i += 256) { float a = sc[i] / denom; sc[i] = a; attn_ws[(size_t)row * NS + i] = a; }
  __syncthreads();
  // phase 2: lerp accumulation, lane = dim
  float ak = 0.f, av = 0.f;
  for (int i = wv; i < NS; i += 4) {
    int idx = sel[i];
    size_t base = ((size_t)idx * NH + h) * ND;
    float a = sc[i];
    ak += a * Kst[base + lane];
    av += a * Vst[base + lane];
  }
  pk[wv][lane] = ak; pv[wv][lane] = av;
  __syncthreads();
  if (tid < ND) {
    lerp_k[(size_t)row * ND + tid] = pk[0][tid] + pk[1][tid] + pk[2][tid] + pk[3][tid];
    lerp_v[(size_t)row * ND + tid] = pv[0][tid] + pv[1][tid] + pv[2][tid] + pv[3][tid];
  }
}

__global__ void k_winner(const int* __restrict__ idx_sel, int* __restrict__ winner) {
  int t = blockIdx.x * blockDim.x + threadIdx.x;
  if (t >= NB * NH * NS) return;
  int row = t >> 10;
  int h = row & 15, b = row >> 4;
  int idx = idx_sel[t];
  atomicMax(&winner[(size_t)idx * NH + h], b);
}

// one wave per (row,i); write only if this b is the last-writer (max b) for (idx,h)
__global__ void __launch_bounds__(256) k_scatter(const float* __restrict__ Kst,
    const float* __restrict__ Vst, const float* __restrict__ Lst,
    const int* __restrict__ idx_sel, const float* __restrict__ attn_ws,
    const int* __restrict__ winner, const float* __restrict__ lerp_k,
    const float* __restrict__ lerp_v, float* __restrict__ outK,
    float* __restrict__ outV, float* __restrict__ outL) {
  int g = blockIdx.x * 4 + (threadIdx.x >> 6);
  int lane = threadIdx.x & 63;
  int row = g >> 10, i = g & 1023;
  int h = row & 15, b = row >> 4;
  int idx = idx_sel[(size_t)row * NS + i];
  if (winner[(size_t)idx * NH + h] != b) return;
  float a = attn_ws[(size_t)row * NS + i];
  size_t base = ((size_t)idx * NH + h) * ND;
  float kv = Kst[base + lane], vv = Vst[base + lane];
  float lk = lerp_k[(size_t)row * ND + lane], lv = lerp_v[(size_t)row * ND + lane];
  outK[base + lane] = (1.0f - a) * kv + a * lk;
  outV[base + lane] = (1.0f - a) * vv + a * lv;
  if (lane == 0) outL[(size_t)idx * NH + h] = 0.99f * Lst[(size_t)idx * NH + h] + a;
}

extern "C" void kernel_launch(void* const* d_in, const int* in_sizes, int n_in,
                              void* d_out, int out_size, void* d_ws, size_t ws_size,
                              hipStream_t stream) {
  const float* q   = (const float*)d_in[0];
  const float* Kst = (const float*)d_in[1];
  const float* Vst = (const float*)d_in[2];
  const float* Lst = (const float*)d_in[3];

  float* out     = (float*)d_out;
  float* out_lk  = out;                       // (B,H,D) = 32768
  float* out_lv  = out + 32768;
  float* outK    = out + 65536;               // (SIZE,H,D) = 268435456
  float* outV    = outK + 268435456;
  float* outL    = outV + 268435456;          // (SIZE,H) = 4194304

  char* ws = (char*)d_ws;
  float* logw   = (float*)ws;                       // 16 MB: (H, SIZE)
  int*   idxsel = (int*)(ws + (16u << 20));         // 2 MB: (B*H, 1024)
  float* attn   = (float*)(ws + (18u << 20));       // 2 MB
  int*   winner = (int*)(ws + (20u << 20));         // 16 MB: (SIZE, H)

  k_logw<<<SZ / 256, 256, 0, stream>>>(Lst, logw, outL, winner);
  k_copy<<<2048, 256, 0, stream>>>((const float4*)Kst, (float4*)outK, 67108864L);
  k_copy<<<2048, 256, 0, stream>>>((const float4*)Vst, (float4*)outV, 67108864L);
  k_select<<<NB * NH, SEL_T, 0, stream>>>(logw, idxsel);
  k_attn<<<NB * NH, 256, 0, stream>>>(q, Kst, Vst, idxsel, attn, out_lk, out_lv);
  k_winner<<<(NB * NH * NS) / 256, 256, 0, stream>>>(idxsel, winner);
  k_scatter<<<(NB * NH * NS) / 4, 256, 0, stream>>>(Kst, Vst, Lst, idxsel, attn, winner,
                                                    out_lk, out_lv, outK, outV, outL);
}

// Round 2
// 1915.957 us; speedup vs baseline: 1.4238x; 1.4238x over previous
//
#include <hip/hip_runtime.h>
#include <stdint.h>

static constexpr int NB = 32, NH = 16, ND = 64, NS = 1024;
static constexpr int SZ = 262144;
static constexpr int NROW = NB * NH;        // 512
static constexpr int NSLOT = SZ * NH;       // 4194304 (s,h) slots

__device__ __forceinline__ uint32_t rotl32(uint32_t x, int r) { return (x << r) | (x >> (32 - r)); }

// Threefry-2x32-20 with key (0, 42): ks = [0, 42, 0x1BD11BDA^42 = 0x1BD11BF0]
__device__ __forceinline__ void tf2x32(uint32_t x0, uint32_t x1, uint32_t& o0, uint32_t& o1) {
  const uint32_t K1 = 42u, K2 = 0x1BD11BF0u;
  x1 += K1;
#define TFR(r) { x0 += x1; x1 = rotl32(x1, (r)); x1 ^= x0; }
  TFR(13) TFR(15) TFR(26) TFR(6)
  x0 += K1; x1 += K2 + 1u;
  TFR(17) TFR(29) TFR(16) TFR(24)
  x0 += K2; x1 += 2u;
  TFR(13) TFR(15) TFR(26) TFR(6)
  x1 += K1 + 3u;
  TFR(17) TFR(29) TFR(16) TFR(24)
  x0 += K1; x1 += K2 + 4u;
  TFR(13) TFR(15) TFR(26) TFR(6)
  x0 += K2; x1 += 5u;
#undef TFR
  o0 = x0; o1 = x1;
}

// jax partitionable threefry: bits = o0 ^ o1 of counter (0, flat_index)
__device__ __forceinline__ float gumbel_of(uint32_t row, uint32_t s) {
  uint32_t p = (row << 18) | s;
  uint32_t o0, o1; tf2x32(0u, p, o0, o1);
  uint32_t bits = o0 ^ o1;
  float f = __uint_as_float((bits >> 9) | 0x3f800000u) - 1.0f;
  float u = fmaxf(1e-12f, f + 1e-12f);
  float t = -logf(u);
  return -logf(t);
}

// order-preserving float -> uint key
__device__ __forceinline__ uint32_t fkey(float v) {
  uint32_t u = __float_as_uint(v);
  return (u & 0x80000000u) ? ~u : (u | 0x80000000u);
}

// logw[h][s] = logit[s][h] - logsumexp_h ; init winner = -1
__global__ void k_logw(const float* __restrict__ logit, float* __restrict__ logw,
                       int* __restrict__ winner) {
  int s = blockIdx.x * blockDim.x + threadIdx.x;
  if (s >= SZ) return;
  const float4* p = (const float4*)(logit + (size_t)s * NH);
  float4 a0 = p[0], a1 = p[1], a2 = p[2], a3 = p[3];
  float x[16] = {a0.x,a0.y,a0.z,a0.w, a1.x,a1.y,a1.z,a1.w,
                 a2.x,a2.y,a2.z,a2.w, a3.x,a3.y,a3.z,a3.w};
  float m = x[0];
#pragma unroll
  for (int h = 1; h < 16; ++h) m = fmaxf(m, x[h]);
  float acc = 0.f;
#pragma unroll
  for (int h = 0; h < 16; ++h) acc += expf(x[h] - m);
  float lse = logf(acc) + m;
#pragma unroll
  for (int h = 0; h < 16; ++h) logw[(size_t)h * SZ + s] = x[h] - lse;
  int4 mone = make_int4(-1, -1, -1, -1);
  int4* w = (int4*)(winner + (size_t)s * NH);
  w[0] = mone; w[1] = mone; w[2] = mone; w[3] = mone;
}

// wave-0 parallel descending-threshold find: T = largest bin b with sum_{b'>b} hist[b'] < need
// and sum_{b'>=b} >= need. Result -> *outT. Caller syncs before and after.
__device__ __forceinline__ void find_thresh(const uint32_t* hist, int nbins, int chunk,
                                            uint32_t need, int* outT, int tid) {
  if (tid < 64) {
    int hi = nbins - 1 - tid * chunk;
    uint32_t csum = 0;
    for (int j = 0; j < chunk; ++j) csum += hist[hi - j];
    uint32_t inc = csum;
#pragma unroll
    for (int off = 1; off < 64; off <<= 1) {
      uint32_t t = (uint32_t)__shfl_up((int)inc, off);
      if (tid >= off) inc += t;
    }
    uint32_t pre = inc - csum;
    if (pre < need && inc >= need) {
      uint32_t cum = pre; int T = hi - chunk + 1;
      for (int j = 0; j < chunk; ++j) {
        int b = hi - j;
        if (cum + hist[b] >= need) { T = b; break; }
        cum += hist[b];
      }
      *outT = T;
    }
  }
}

#define SEL_T 512
template<bool CACHED>
__global__ void __launch_bounds__(SEL_T) k_select(const float* __restrict__ logw,
                                                  uint32_t* __restrict__ keys_g,
                                                  int* __restrict__ idx_sel) {
  const int row = blockIdx.x;
  const int h = row & 15;
  const float* lw = logw + (size_t)h * SZ;
  uint32_t* keys = keys_g + (size_t)row * SZ;
  int* outrow = idx_sel + (size_t)row * NS;
  __shared__ uint32_t hist[4096];
  __shared__ int cand[4096];
  __shared__ int cand2[256];
  __shared__ int cand3[64];
  __shared__ int ctl[8]; // 0:nsel 1:ncand 2:T 3:ncand2 4:ncand3
  const int tid = threadIdx.x;

  for (int i = tid; i < 4096; i += SEL_T) hist[i] = 0;
  if (tid < 8) ctl[tid] = 0;
  __syncthreads();
  // pass A: 12-bit histogram, ILP-2 (two independent threefry chains in flight)
  for (int s = tid; s < SZ; s += 2 * SEL_T) {
    int s2 = s + SEL_T;
    float v1 = lw[s]  + gumbel_of(row, s);
    float v2 = lw[s2] + gumbel_of(row, s2);
    uint32_t k1 = fkey(v1), k2 = fkey(v2);
    if (CACHED) { keys[s] = k1; keys[s2] = k2; }
    atomicAdd(&hist[k1 >> 20], 1u);
    atomicAdd(&hist[k2 >> 20], 1u);
  }
  __syncthreads();
  find_thresh(hist, 4096, 64, (uint32_t)NS, &ctl[2], tid);
  __syncthreads();
  const int T0 = ctl[2];
  // pass B: accept bins > T0, collect bin == T0
  for (int s = tid; s < SZ; s += SEL_T) {
    uint32_t key = CACHED ? keys[s] : fkey(lw[s] + gumbel_of(row, s));
    int b = key >> 20;
    if (b > T0)       { int p = atomicAdd(&ctl[0], 1); outrow[p] = s; }
    else if (b == T0) { int c = atomicAdd(&ctl[1], 1); if (c < 4096) cand[c] = s; }
  }
  __syncthreads();
  // level 2: next 12 bits among candidates
  const int C = min(ctl[1], 4096);
  for (int i = tid; i < 4096; i += SEL_T) hist[i] = 0;
  if (tid == 0) ctl[3] = 0;
  __syncthreads();
  for (int ci = tid; ci < C; ci += SEL_T) {
    int s = cand[ci];
    uint32_t key = CACHED ? keys[s] : fkey(lw[s] + gumbel_of(row, s));
    atomicAdd(&hist[(key >> 8) & 0xFFFu], 1u);
  }
  __syncthreads();
  find_thresh(hist, 4096, 64, (uint32_t)(NS - ctl[0]), &ctl[2], tid);
  __syncthreads();
  const int T1 = ctl[2];
  for (int ci = tid; ci < C; ci += SEL_T) {
    int s = cand[ci];
    uint32_t key = CACHED ? keys[s] : fkey(lw[s] + gumbel_of(row, s));
    int mid = (key >> 8) & 0xFFF;
    if (mid > T1)       { int p = atomicAdd(&ctl[0], 1); outrow[p] = s; }
    else if (mid == T1) { int c = atomicAdd(&ctl[3], 1); if (c < 256) cand2[c] = s; }
  }
  __syncthreads();
  // level 3: low 8 bits
  const int C2 = min(ctl[3], 256);
  if (tid < 256) hist[tid] = 0;
  if (tid == 0) ctl[4] = 0;
  __syncthreads();
  for (int ci = tid; ci < C2; ci += SEL_T) {
    int s = cand2[ci];
    uint32_t key = CACHED ? keys[s] : fkey(lw[s] + gumbel_of(row, s));
    atomicAdd(&hist[key & 0xFFu], 1u);
  }
  __syncthreads();
  find_thresh(hist, 256, 4, (uint32_t)(NS - ctl[0]), &ctl[2], tid);
  __syncthreads();
  const int T2 = ctl[2];
  for (int ci = tid; ci < C2; ci += SEL_T) {
    int s = cand2[ci];
    uint32_t key = CACHED ? keys[s] : fkey(lw[s] + gumbel_of(row, s));
    int lo = key & 0xFF;
    if (lo > T2)       { int p = atomicAdd(&ctl[0], 1); outrow[p] = s; }
    else if (lo == T2) { int c = atomicAdd(&ctl[4], 1); if (c < 64) cand3[c] = s; }
  }
  __syncthreads();
  if (tid == 0) {
    int need = NS - ctl[0];
    int c3 = min(ctl[4], 64);
    for (int k = 0; k < need; ++k) {  // exact-key ties: smallest index first (top_k semantics)
      int best = 0x7fffffff, bi = 0;
      for (int j = 0; j < c3; ++j) if (cand3[j] < best) { best = cand3[j]; bi = j; }
      if (best == 0x7fffffff) best = 0;
      outrow[ctl[0] + k] = best;
      if (c3 > 0) cand3[bi] = 0x7fffffff;
    }
  }
}

// per row (b,h): scores -> softmax -> attn (ws) + lerp_k/lerp_v (d_out) + winner atomicMax
__global__ void __launch_bounds__(256) k_attn(const float* __restrict__ qin,
    const float* __restrict__ Kst, const float* __restrict__ Vst,
    const int* __restrict__ idx_sel, float* __restrict__ attn_ws,
    float* __restrict__ lerp_k, float* __restrict__ lerp_v, int* __restrict__ winner) {
  const int row = blockIdx.x;
  const int h = row & 15, b = row >> 4;
  const int tid = threadIdx.x;
  const int lane = tid & 63, wv = tid >> 6;
  __shared__ float sc[NS];
  __shared__ int sel_s[NS];
  __shared__ float red[256];
  __shared__ float pk[4][ND], pv[4][ND];
  const int* sel = idx_sel + (size_t)row * NS;
  for (int i = tid; i < NS; i += 256) sel_s[i] = sel[i];
  float qd = qin[(size_t)row * ND + lane];
  __syncthreads();
  // phase 1: one wave per score, 2 in flight
  for (int i = wv; i < NS; i += 8) {
    int i2 = i + 4;
    int idx1 = sel_s[i], idx2 = sel_s[i2];
    float p1 = qd * Kst[((size_t)idx1 * NH + h) * ND + lane];
    float p2 = qd * Kst[((size_t)idx2 * NH + h) * ND + lane];
#pragma unroll
    for (int off = 32; off; off >>= 1) { p1 += __shfl_xor(p1, off); p2 += __shfl_xor(p2, off); }
    if (lane == 0) { sc[i] = p1 * 0.125f; sc[i2] = p2 * 0.125f; }
  }
  __syncthreads();
  // softmax
  float m = -1e30f;
  for (int i = tid; i < NS; i += 256) m = fmaxf(m, sc[i]);
  red[tid] = m; __syncthreads();
  for (int w = 128; w; w >>= 1) { if (tid < w) red[tid] = fmaxf(red[tid], red[tid + w]); __syncthreads(); }
  m = red[0]; __syncthreads();
  float ssum = 0.f;
  for (int i = tid; i < NS; i += 256) { float e = expf(sc[i] - m); sc[i] = e; ssum += e; }
  red[tid] = ssum; __syncthreads();
  for (int w = 128; w; w >>= 1) { if (tid < w) red[tid] += red[tid + w]; __syncthreads(); }
  float denom = red[0]; __syncthreads();
  for (int i = tid; i < NS; i += 256) { float a = sc[i] / denom; sc[i] = a; attn_ws[(size_t)row * NS + i] = a; }
  __syncthreads();
  // phase 2: lerp accumulation, lane = dim
  float ak = 0.f, av = 0.f;
  for (int i = wv; i < NS; i += 4) {
    int idx = sel_s[i];
    size_t base = ((size_t)idx * NH + h) * ND;
    float a = sc[i];
    ak += a * Kst[base + lane];
    av += a * Vst[base + lane];
  }
  pk[wv][lane] = ak; pv[wv][lane] = av;
  __syncthreads();
  if (tid < ND) {
    lerp_k[(size_t)row * ND + tid] = pk[0][tid] + pk[1][tid] + pk[2][tid] + pk[3][tid];
    lerp_v[(size_t)row * ND + tid] = pv[0][tid] + pv[1][tid] + pv[2][tid] + pv[3][tid];
  }
  // winner map: last-write-wins over b  <=> max b per (idx,h)
  for (int i = tid; i < NS; i += 256) atomicMax(&winner[(size_t)sel_s[i] * NH + h], b);
}

// winning attn weight per slot (unique winner row per (idx,h))
__global__ void k_mark(const int* __restrict__ idx_sel, const float* __restrict__ attn_ws,
                       const int* __restrict__ winner, float* __restrict__ wa) {
  int t = blockIdx.x * 256 + threadIdx.x;   // NROW*NS threads exactly
  int row = t >> 10, h = row & 15, b = row >> 4;
  int idx = idx_sel[t];
  if (winner[(size_t)idx * NH + h] == b) wa[(size_t)idx * NH + h] = attn_ws[t];
}

// fused copy + scatter: one pass over all slots, passthrough or blend
__global__ void __launch_bounds__(256) k_emit(const float4* __restrict__ K4,
    const float4* __restrict__ V4, const float* __restrict__ Lst,
    const int* __restrict__ winner, const float* __restrict__ wa,
    const float4* __restrict__ LK4, const float4* __restrict__ LV4,
    float4* __restrict__ oK4, float4* __restrict__ oV4, float* __restrict__ outL) {
  const long NF4 = (long)NSLOT * 16;        // 67,108,864 float4 per store
  long i = (long)blockIdx.x * 256 + threadIdx.x;
  const long stride = (long)gridDim.x * 256;
  for (; i < NF4; i += stride) {
    int slot = (int)(i >> 4);
    int w = winner[slot];
    float4 kv = K4[i], vv = V4[i];
    if (w >= 0) {
      float a = wa[slot];
      int row = (w << 4) | (slot & 15);
      float4 lk = LK4[((long)row << 4) + (i & 15)];
      float4 lv = LV4[((long)row << 4) + (i & 15)];
      float o = 1.0f - a;
      kv = make_float4(o*kv.x + a*lk.x, o*kv.y + a*lk.y, o*kv.z + a*lk.z, o*kv.w + a*lk.w);
      vv = make_float4(o*vv.x + a*lv.x, o*vv.y + a*lv.y, o*vv.z + a*lv.z, o*vv.w + a*lv.w);
      if ((i & 15) == 0) outL[slot] = 0.99f * Lst[slot] + a;
    } else if ((i & 15) == 0) {
      outL[slot] = Lst[slot];
    }
    oK4[i] = kv; oV4[i] = vv;
  }
}

extern "C" void kernel_launch(void* const* d_in, const int* in_sizes, int n_in,
                              void* d_out, int out_size, void* d_ws, size_t ws_size,
                              hipStream_t stream) {
  const float* q   = (const float*)d_in[0];
  const float* Kst = (const float*)d_in[1];
  const float* Vst = (const float*)d_in[2];
  const float* Lst = (const float*)d_in[3];

  float* out    = (float*)d_out;
  float* out_lk = out;                        // (B,H,D)
  float* out_lv = out + 32768;
  float* outK   = out + 65536;                // (SIZE,H,D)
  float* outV   = outK + 268435456;
  float* outL   = outV + 268435456;           // (SIZE,H)

  char* ws = (char*)d_ws;
  float*    logw   = (float*)ws;                         // 16 MB (H,SIZE)
  int*      idxsel = (int*)(ws + (16ull << 20));         //  2 MB (NROW,NS)
  float*    attn   = (float*)(ws + (18ull << 20));       //  2 MB
  int*      winner = (int*)(ws + (20ull << 20));         // 16 MB (SIZE,H)
  float*    wa     = (float*)(ws + (36ull << 20));       // 16 MB (SIZE,H)
  uint32_t* keys   = (uint32_t*)(ws + (52ull << 20));    // 512 MB (NROW,SIZE) if available
  const bool cached = ws_size >= (564ull << 20);

  k_logw<<<SZ / 256, 256, 0, stream>>>(Lst, logw, winner);
  if (cached)
    k_select<true ><<<NROW, SEL_T, 0, stream>>>(logw, keys, idxsel);
  else
    k_select<false><<<NROW, SEL_T, 0, stream>>>(logw, keys, idxsel);
  k_attn<<<NROW, 256, 0, stream>>>(q, Kst, Vst, idxsel, attn, out_lk, out_lv, winner);
  k_mark<<<NROW * NS / 256, 256, 0, stream>>>(idxsel, attn, winner, wa);
  k_emit<<<8192, 256, 0, stream>>>((const float4*)Kst, (const float4*)Vst, Lst,
                                   winner, wa, (const float4*)out_lk, (const float4*)out_lv,
                                   (float4*)outK, (float4*)outV, outL);
}

// Round 3
// 1512.672 us; speedup vs baseline: 1.8034x; 1.2666x over previous
//
#include <hip/hip_runtime.h>
#include <stdint.h>

static constexpr int NB = 32, NH = 16, ND = 64, NS = 1024;
static constexpr int SZ = 262144;
static constexpr int NROW = NB * NH;        // 512
static constexpr int NSLOT = SZ * NH;       // 4194304 (s,h) slots

typedef float f32x4 __attribute__((ext_vector_type(4)));

__device__ __forceinline__ uint32_t rotl32(uint32_t x, int r) { return (x << r) | (x >> (32 - r)); }

// Threefry-2x32-20 with key (0, 42): ks = [0, 42, 0x1BD11BDA^42 = 0x1BD11BF0]
__device__ __forceinline__ void tf2x32(uint32_t x0, uint32_t x1, uint32_t& o0, uint32_t& o1) {
  const uint32_t K1 = 42u, K2 = 0x1BD11BF0u;
  x1 += K1;
#define TFR(r) { x0 += x1; x1 = rotl32(x1, (r)); x1 ^= x0; }
  TFR(13) TFR(15) TFR(26) TFR(6)
  x0 += K1; x1 += K2 + 1u;
  TFR(17) TFR(29) TFR(16) TFR(24)
  x0 += K2; x1 += 2u;
  TFR(13) TFR(15) TFR(26) TFR(6)
  x1 += K1 + 3u;
  TFR(17) TFR(29) TFR(16) TFR(24)
  x0 += K1; x1 += K2 + 4u;
  TFR(13) TFR(15) TFR(26) TFR(6)
  x0 += K2; x1 += 5u;
#undef TFR
  o0 = x0; o1 = x1;
}

__device__ __forceinline__ uint32_t bits_of(uint32_t row, uint32_t s) {
  uint32_t o0, o1; tf2x32(0u, (row << 18) | s, o0, o1);
  return o0 ^ o1;
}

// precise gumbel (matches reference float path closely; used for candidate re-key only)
__device__ __forceinline__ float gumbel_precise(uint32_t row, uint32_t s) {
  uint32_t bits = bits_of(row, s);
  float f = __uint_as_float((bits >> 9) | 0x3f800000u) - 1.0f;
  float u = fmaxf(1e-12f, f + 1e-12f);
  float t = -logf(u);
  return -logf(t);
}

// fast gumbel via v_log_f32 (|err| ~4e-7 abs; only used for candidate filtering with
// a ~rank-4096 threshold margin, so boundary-safe)
__device__ __forceinline__ float gumbel_fast(uint32_t row, uint32_t s) {
  uint32_t bits = bits_of(row, s);
  float f = __uint_as_float((bits >> 9) | 0x3f800000u) - 1.0f;
  float u = fmaxf(1e-12f, f + 1e-12f);
  float t = -0.69314718056f * __log2f(u);   // -log(u) > 0
  return -0.69314718056f * __log2f(t);
}

// order-preserving float -> uint key
__device__ __forceinline__ uint32_t fkey(float v) {
  uint32_t u = __float_as_uint(v);
  return (u & 0x80000000u) ? ~u : (u | 0x80000000u);
}

// logw[h][s] = logit[s][h] - logsumexp_h ; init winner = -1
__global__ void k_logw(const float* __restrict__ logit, float* __restrict__ logw,
                       int* __restrict__ winner) {
  int s = blockIdx.x * blockDim.x + threadIdx.x;
  if (s >= SZ) return;
  const float4* p = (const float4*)(logit + (size_t)s * NH);
  float4 a0 = p[0], a1 = p[1], a2 = p[2], a3 = p[3];
  float x[16] = {a0.x,a0.y,a0.z,a0.w, a1.x,a1.y,a1.z,a1.w,
                 a2.x,a2.y,a2.z,a2.w, a3.x,a3.y,a3.z,a3.w};
  float m = x[0];
#pragma unroll
  for (int h = 1; h < 16; ++h) m = fmaxf(m, x[h]);
  float acc = 0.f;
#pragma unroll
  for (int h = 0; h < 16; ++h) acc += expf(x[h] - m);
  float lse = logf(acc) + m;
#pragma unroll
  for (int h = 0; h < 16; ++h) logw[(size_t)h * SZ + s] = x[h] - lse;
  int4 mone = make_int4(-1, -1, -1, -1);
  int4* w = (int4*)(winner + (size_t)s * NH);
  w[0] = mone; w[1] = mone; w[2] = mone; w[3] = mone;
}

// parallel descending-threshold find on wave 0: T = largest bin b with
// above(b) < need <= above(b) + hist[b]; writes T to *outT and above(T) to *outAbove.
__device__ __forceinline__ void find_thresh(const uint32_t* hist, int nbins, int chunk,
                                            uint32_t need, int* outT, uint32_t* outAbove,
                                            int tid) {
  if (tid < 64) {
    int hi = nbins - 1 - tid * chunk;
    uint32_t csum = 0;
    for (int j = 0; j < chunk; ++j) csum += hist[hi - j];
    uint32_t inc = csum;
#pragma unroll
    for (int off = 1; off < 64; off <<= 1) {
      uint32_t t = (uint32_t)__shfl_up((int)inc, off);
      if (tid >= off) inc += t;
    }
    uint32_t pre = inc - csum;
    if (pre < need && inc >= need) {
      uint32_t cum = pre; int T = hi - chunk + 1;
      for (int j = 0; j < chunk; ++j) {
        int b = hi - j;
        if (cum + hist[b] >= need) { T = b; break; }
        cum += hist[b];
      }
      *outT = T; *outAbove = cum;
    }
  }
}

#define SEL_T 1024
#define NCAND 8192
// exact top-1024 per row: sampled Tlo -> single full pass (fast keys) -> precise re-key of
// ~4K candidates -> exact 3-level radix select. Ties at exact key -> smallest s.
__global__ void __launch_bounds__(SEL_T) k_select(const float* __restrict__ logw,
                                                  int* __restrict__ idx_sel) {
  const int row = blockIdx.x;
  const int h = row & 15;
  const float* lw = logw + (size_t)h * SZ;
  int* outrow = idx_sel + (size_t)row * NS;
  __shared__ uint32_t ckey[NCAND];   // 32 KB (sample keys, then candidate keys)
  __shared__ int      cidx[NCAND];   // 32 KB
  __shared__ uint32_t hist[4096];    // 16 KB
  __shared__ int      candA[4096];   // 16 KB
  __shared__ int      candB[256];
  __shared__ int      candC[64];
  __shared__ int      ctl[8];        // 0:nsel 1:ncand 2:T 3:CA 4:CB 5:CC 6:above
  const int tid = threadIdx.x;

  // ---- stage 0: sample every 32nd item with fast keys ----
#pragma unroll
  for (int j = 0; j < 8; ++j) {
    int k = tid + j * SEL_T;
    int s = k << 5;
    ckey[k] = fkey(lw[s] + gumbel_fast(row, s));
  }
  for (int i = tid; i < 4096; i += SEL_T) hist[i] = 0;
  if (tid < 8) ctl[tid] = 0;
  __syncthreads();
#pragma unroll
  for (int j = 0; j < 8; ++j) atomicAdd(&hist[ckey[tid + j * SEL_T] >> 20], 1u);
  __syncthreads();
  find_thresh(hist, 4096, 64, 128u, &ctl[2], (uint32_t*)&ctl[6], tid);
  __syncthreads();
  const uint32_t T0a = (uint32_t)ctl[2];
  const uint32_t aboveA = (uint32_t)ctl[6];
  for (int i = tid; i < 4096; i += SEL_T) hist[i] = 0;
  __syncthreads();
#pragma unroll
  for (int j = 0; j < 8; ++j) {
    uint32_t k = ckey[tid + j * SEL_T];
    if ((k >> 20) == T0a) atomicAdd(&hist[(k >> 8) & 0xFFFu], 1u);
  }
  __syncthreads();
  find_thresh(hist, 4096, 64, 128u - aboveA, &ctl[2], (uint32_t*)&ctl[6], tid);
  __syncthreads();
  const uint32_t Tlo = (T0a << 20) | ((uint32_t)ctl[2] << 8);
  if (tid == 0) ctl[1] = 0;
  __syncthreads();

  // ---- stage 1: full pass, append candidates >= Tlo (fast keys), ILP-2 ----
  for (int s = tid; s < SZ; s += 2 * SEL_T) {
    int s2 = s + SEL_T;
    uint32_t k1 = fkey(lw[s]  + gumbel_fast(row, s));
    uint32_t k2 = fkey(lw[s2] + gumbel_fast(row, s2));
    if (k1 >= Tlo) { int p = atomicAdd(&ctl[1], 1); if (p < NCAND) { ckey[p] = k1; cidx[p] = s; } }
    if (k2 >= Tlo) { int p = atomicAdd(&ctl[1], 1); if (p < NCAND) { ckey[p] = k2; cidx[p] = s2; } }
  }
  __syncthreads();
  const int C = min(ctl[1], NCAND);

  // ---- stage 2: precise re-key of candidates + level-1 histogram ----
  for (int i = tid; i < 4096; i += SEL_T) hist[i] = 0;
  if (tid == 0) { ctl[0] = 0; ctl[3] = 0; ctl[4] = 0; ctl[5] = 0; }
  __syncthreads();
  for (int ci = tid; ci < C; ci += SEL_T) {
    int s = cidx[ci];
    uint32_t k = fkey(lw[s] + gumbel_precise(row, s));
    ckey[ci] = k;
    atomicAdd(&hist[k >> 20], 1u);
  }
  __syncthreads();
  find_thresh(hist, 4096, 64, (uint32_t)NS, &ctl[2], (uint32_t*)&ctl[6], tid);
  __syncthreads();
  const int T0 = ctl[2];
  for (int ci = tid; ci < C; ci += SEL_T) {
    int b = (int)(ckey[ci] >> 20);
    if (b > T0)       { int p = atomicAdd(&ctl[0], 1); outrow[p] = cidx[ci]; }
    else if (b == T0) { int c = atomicAdd(&ctl[3], 1); if (c < 4096) candA[c] = ci; }
  }
  __syncthreads();
  const int CA = min(ctl[3], 4096);
  for (int i = tid; i < 4096; i += SEL_T) hist[i] = 0;
  __syncthreads();
  for (int i = tid; i < CA; i += SEL_T) atomicAdd(&hist[(ckey[candA[i]] >> 8) & 0xFFFu], 1u);
  __syncthreads();
  find_thresh(hist, 4096, 64, (uint32_t)(NS - ctl[0]), &ctl[2], (uint32_t*)&ctl[6], tid);
  __syncthreads();
  const int T1 = ctl[2];
  for (int i = tid; i < CA; i += SEL_T) {
    int ci = candA[i];
    int mid = (int)((ckey[ci] >> 8) & 0xFFFu);
    if (mid > T1)       { int p = atomicAdd(&ctl[0], 1); outrow[p] = cidx[ci]; }
    else if (mid == T1) { int c = atomicAdd(&ctl[4], 1); if (c < 256) candB[c] = ci; }
  }
  __syncthreads();
  const int CB = min(ctl[4], 256);
  if (tid < 256) hist[tid] = 0;
  __syncthreads();
  for (int i = tid; i < CB; i += SEL_T) atomicAdd(&hist[ckey[candB[i]] & 0xFFu], 1u);
  __syncthreads();
  find_thresh(hist, 256, 4, (uint32_t)(NS - ctl[0]), &ctl[2], (uint32_t*)&ctl[6], tid);
  __syncthreads();
  const int T2 = ctl[2];
  for (int i = tid; i < CB; i += SEL_T) {
    int ci = candB[i];
    int lo = (int)(ckey[ci] & 0xFFu);
    if (lo > T2)       { int p = atomicAdd(&ctl[0], 1); outrow[p] = cidx[ci]; }
    else if (lo == T2) { int c = atomicAdd(&ctl[5], 1); if (c < 64) candC[c] = ci; }
  }
  __syncthreads();
  if (tid == 0) {
    int need = NS - ctl[0];
    int cc = min(ctl[5], 64);
    for (int k = 0; k < need; ++k) {  // exact-key ties: smallest index first (top_k semantics)
      int best = 0x7fffffff, bi = 0;
      for (int j = 0; j < cc; ++j) { int s = cidx[candC[j]]; if (s < best) { best = s; bi = j; } }
      if (best == 0x7fffffff) best = 0;
      outrow[ctl[0] + k] = best;
      if (cc > 0) cidx[candC[bi]] = 0x7fffffff;
    }
  }
}

// per row (b,h): scores -> softmax -> attn (ws) + lerp_k/lerp_v (d_out) + winner atomicMax
__global__ void __launch_bounds__(256) k_attn(const float* __restrict__ qin,
    const float* __restrict__ Kst, const float* __restrict__ Vst,
    const int* __restrict__ idx_sel, float* __restrict__ attn_ws,
    float* __restrict__ lerp_k, float* __restrict__ lerp_v, int* __restrict__ winner) {
  const int row = blockIdx.x;
  const int h = row & 15, b = row >> 4;
  const int tid = threadIdx.x;
  const int lane = tid & 63, wv = tid >> 6;
  __shared__ float sc[NS];
  __shared__ int sel_s[NS];
  __shared__ float red[256];
  __shared__ float pk[4][ND], pv[4][ND];
  const int* sel = idx_sel + (size_t)row * NS;
  for (int i = tid; i < NS; i += 256) sel_s[i] = sel[i];
  float qd = qin[(size_t)row * ND + lane];
  __syncthreads();
  // phase 1: one wave per score, 2 in flight
  for (int i = wv; i < NS; i += 8) {
    int i2 = i + 4;
    int idx1 = sel_s[i], idx2 = sel_s[i2];
    float p1 = qd * Kst[((size_t)idx1 * NH + h) * ND + lane];
    float p2 = qd * Kst[((size_t)idx2 * NH + h) * ND + lane];
#pragma unroll
    for (int off = 32; off; off >>= 1) { p1 += __shfl_xor(p1, off); p2 += __shfl_xor(p2, off); }
    if (lane == 0) { sc[i] = p1 * 0.125f; sc[i2] = p2 * 0.125f; }
  }
  __syncthreads();
  // softmax
  float m = -1e30f;
  for (int i = tid; i < NS; i += 256) m = fmaxf(m, sc[i]);
  red[tid] = m; __syncthreads();
  for (int w = 128; w; w >>= 1) { if (tid < w) red[tid] = fmaxf(red[tid], red[tid + w]); __syncthreads(); }
  m = red[0]; __syncthreads();
  float ssum = 0.f;
  for (int i = tid; i < NS; i += 256) { float e = expf(sc[i] - m); sc[i] = e; ssum += e; }
  red[tid] = ssum; __syncthreads();
  for (int w = 128; w; w >>= 1) { if (tid < w) red[tid] += red[tid + w]; __syncthreads(); }
  float denom = red[0]; __syncthreads();
  for (int i = tid; i < NS; i += 256) { float a = sc[i] / denom; sc[i] = a; attn_ws[(size_t)row * NS + i] = a; }
  __syncthreads();
  // phase 2: lerp accumulation, lane = dim, ILP-2 (4 loads in flight)
  float ak = 0.f, av = 0.f;
  for (int i = wv; i < NS; i += 8) {
    int i2 = i + 4;
    int idx1 = sel_s[i], idx2 = sel_s[i2];
    size_t b1 = ((size_t)idx1 * NH + h) * ND, b2 = ((size_t)idx2 * NH + h) * ND;
    float a1 = sc[i], a2 = sc[i2];
    float k1 = Kst[b1 + lane], v1 = Vst[b1 + lane];
    float k2 = Kst[b2 + lane], v2 = Vst[b2 + lane];
    ak += a1 * k1 + a2 * k2;
    av += a1 * v1 + a2 * v2;
  }
  pk[wv][lane] = ak; pv[wv][lane] = av;
  __syncthreads();
  if (tid < ND) {
    lerp_k[(size_t)row * ND + tid] = pk[0][tid] + pk[1][tid] + pk[2][tid] + pk[3][tid];
    lerp_v[(size_t)row * ND + tid] = pv[0][tid] + pv[1][tid] + pv[2][tid] + pv[3][tid];
  }
  // winner map: last-write-wins over b  <=> max b per (idx,h)
  for (int i = tid; i < NS; i += 256) atomicMax(&winner[(size_t)sel_s[i] * NH + h], b);
}

// winning attn weight per slot (unique winner row per (idx,h))
__global__ void k_mark(const int* __restrict__ idx_sel, const float* __restrict__ attn_ws,
                       const int* __restrict__ winner, float* __restrict__ wa) {
  int t = blockIdx.x * 256 + threadIdx.x;   // NROW*NS threads exactly
  int row = t >> 10, h = row & 15, b = row >> 4;
  int idx = idx_sel[t];
  if (winner[(size_t)idx * NH + h] == b) wa[(size_t)idx * NH + h] = attn_ws[t];
}

// fused copy + scatter: one pass over all slots, passthrough or blend (nontemporal streams)
__global__ void __launch_bounds__(256) k_emit(const f32x4* __restrict__ K4,
    const f32x4* __restrict__ V4, const float* __restrict__ Lst,
    const int* __restrict__ winner, const float* __restrict__ wa,
    const f32x4* __restrict__ LK4, const f32x4* __restrict__ LV4,
    f32x4* __restrict__ oK4, f32x4* __restrict__ oV4, float* __restrict__ outL) {
  const long NF4 = (long)NSLOT * 16;        // 67,108,864 float4 per store
  long i = (long)blockIdx.x * 256 + threadIdx.x;
  const long stride = (long)gridDim.x * 256;
  for (; i < NF4; i += stride) {
    int slot = (int)(i >> 4);
    int w = winner[slot];
    f32x4 kv = __builtin_nontemporal_load(&K4[i]);
    f32x4 vv = __builtin_nontemporal_load(&V4[i]);
    if (w >= 0) {
      float a = wa[slot];
      int row = (w << 4) | (slot & 15);
      f32x4 lk = LK4[((long)row << 4) + (i & 15)];
      f32x4 lv = LV4[((long)row << 4) + (i & 15)];
      float o = 1.0f - a;
      kv = o * kv + a * lk;
      vv = o * vv + a * lv;
      if ((i & 15) == 0) outL[slot] = 0.99f * Lst[slot] + a;
    } else if ((i & 15) == 0) {
      outL[slot] = Lst[slot];
    }
    __builtin_nontemporal_store(kv, &oK4[i]);
    __builtin_nontemporal_store(vv, &oV4[i]);
  }
}

extern "C" void kernel_launch(void* const* d_in, const int* in_sizes, int n_in,
                              void* d_out, int out_size, void* d_ws, size_t ws_size,
                              hipStream_t stream) {
  const float* q   = (const float*)d_in[0];
  const float* Kst = (const float*)d_in[1];
  const float* Vst = (const float*)d_in[2];
  const float* Lst = (const float*)d_in[3];

  float* out    = (float*)d_out;
  float* out_lk = out;                        // (B,H,D)
  float* out_lv = out + 32768;
  float* outK   = out + 65536;                // (SIZE,H,D)
  float* outV   = outK + 268435456;
  float* outL   = outV + 268435456;           // (SIZE,H)

  char* ws = (char*)d_ws;
  float* logw   = (float*)ws;                         // 16 MB (H,SIZE)
  int*   idxsel = (int*)(ws + (16ull << 20));         //  2 MB (NROW,NS)
  float* attn   = (float*)(ws + (18ull << 20));       //  2 MB
  int*   winner = (int*)(ws + (20ull << 20));         // 16 MB (SIZE,H)
  float* wa     = (float*)(ws + (36ull << 20));       // 16 MB (SIZE,H)

  k_logw<<<SZ / 256, 256, 0, stream>>>(Lst, logw, winner);
  k_select<<<NROW, SEL_T, 0, stream>>>(logw, idxsel);
  k_attn<<<NROW, 256, 0, stream>>>(q, Kst, Vst, idxsel, attn, out_lk, out_lv, winner);
  k_mark<<<NROW * NS / 256, 256, 0, stream>>>(idxsel, attn, winner, wa);
  k_emit<<<8192, 256, 0, stream>>>((const f32x4*)Kst, (const f32x4*)Vst, Lst,
                                   winner, wa, (const f32x4*)out_lk, (const f32x4*)out_lv,
                                   (f32x4*)outK, (f32x4*)outV, outL);
}

// Round 4
// 1411.329 us; speedup vs baseline: 1.9329x; 1.0718x over previous
//
#include <hip/hip_runtime.h>
#include <stdint.h>

static constexpr int NB = 32, NH = 16, ND = 64, NS = 1024;
static constexpr int SZ = 262144;
static constexpr int NROW = NB * NH;        // 512
static constexpr int NSLOT = SZ * NH;       // 4194304 (s,h) slots

typedef float f32x4 __attribute__((ext_vector_type(4)));

__device__ __forceinline__ uint32_t rotl32(uint32_t x, int r) { return (x << r) | (x >> (32 - r)); }

// Threefry-2x32-20 with key (0, 42): ks = [0, 42, 0x1BD11BDA^42 = 0x1BD11BF0]
__device__ __forceinline__ void tf2x32(uint32_t x0, uint32_t x1, uint32_t& o0, uint32_t& o1) {
  const uint32_t K1 = 42u, K2 = 0x1BD11BF0u;
  x1 += K1;
#define TFR(r) { x0 += x1; x1 = rotl32(x1, (r)); x1 ^= x0; }
  TFR(13) TFR(15) TFR(26) TFR(6)
  x0 += K1; x1 += K2 + 1u;
  TFR(17) TFR(29) TFR(16) TFR(24)
  x0 += K2; x1 += 2u;
  TFR(13) TFR(15) TFR(26) TFR(6)
  x1 += K1 + 3u;
  TFR(17) TFR(29) TFR(16) TFR(24)
  x0 += K1; x1 += K2 + 4u;
  TFR(13) TFR(15) TFR(26) TFR(6)
  x0 += K2; x1 += 5u;
#undef TFR
  o0 = x0; o1 = x1;
}

__device__ __forceinline__ uint32_t bits_of(uint32_t row, uint32_t s) {
  uint32_t o0, o1; tf2x32(0u, (row << 18) | s, o0, o1);
  return o0 ^ o1;
}

// precise gumbel (reference float path; decides the final selected set)
__device__ __forceinline__ float gumbel_precise(uint32_t row, uint32_t s) {
  uint32_t bits = bits_of(row, s);
  float f = __uint_as_float((bits >> 9) | 0x3f800000u) - 1.0f;
  float u = fmaxf(1e-12f, f + 1e-12f);
  float t = -logf(u);
  return -logf(t);
}

// fast gumbel (stage-0 sampling only)
__device__ __forceinline__ float gumbel_fast(uint32_t row, uint32_t s) {
  uint32_t bits = bits_of(row, s);
  float f = __uint_as_float((bits >> 9) | 0x3f800000u) - 1.0f;
  float u = fmaxf(1e-12f, f + 1e-12f);
  float t = -0.69314718056f * __log2f(u);
  return -0.69314718056f * __log2f(t);
}

// filter primitive: log2(u) for the one-transcendental candidate test
__device__ __forceinline__ float log2u(uint32_t row, uint32_t s) {
  uint32_t bits = bits_of(row, s);
  float f = __uint_as_float((bits >> 9) | 0x3f800000u) - 1.0f;
  float u = fmaxf(1e-12f, f + 1e-12f);
  return __log2f(u);   // in [-39.9, 0]
}

// order-preserving float <-> uint key
__device__ __forceinline__ uint32_t fkey(float v) {
  uint32_t u = __float_as_uint(v);
  return (u & 0x80000000u) ? ~u : (u | 0x80000000u);
}
__device__ __forceinline__ float inv_fkey(uint32_t k) {
  uint32_t u = (k & 0x80000000u) ? (k ^ 0x80000000u) : ~k;
  return __uint_as_float(u);
}

// logw/wexp per (h,s); outL = copy of Lst; winner = -1
__global__ void k_logw(const float* __restrict__ logit, float* __restrict__ logw,
                       float* __restrict__ wexp, float* __restrict__ outL,
                       int* __restrict__ winner) {
  int s = blockIdx.x * blockDim.x + threadIdx.x;
  if (s >= SZ) return;
  const float4* p = (const float4*)(logit + (size_t)s * NH);
  float4 a0 = p[0], a1 = p[1], a2 = p[2], a3 = p[3];
  float x[16] = {a0.x,a0.y,a0.z,a0.w, a1.x,a1.y,a1.z,a1.w,
                 a2.x,a2.y,a2.z,a2.w, a3.x,a3.y,a3.z,a3.w};
  float m = x[0];
#pragma unroll
  for (int h = 1; h < 16; ++h) m = fmaxf(m, x[h]);
  float acc = 0.f;
#pragma unroll
  for (int h = 0; h < 16; ++h) acc += expf(x[h] - m);
  float lse = logf(acc) + m;
#pragma unroll
  for (int h = 0; h < 16; ++h) {
    float lw = x[h] - lse;
    logw[(size_t)h * SZ + s] = lw;
    wexp[(size_t)h * SZ + s] = expf(lw);
  }
  float4* q = (float4*)(outL + (size_t)s * NH);
  q[0] = a0; q[1] = a1; q[2] = a2; q[3] = a3;
  int4 mone = make_int4(-1, -1, -1, -1);
  int4* w = (int4*)(winner + (size_t)s * NH);
  w[0] = mone; w[1] = mone; w[2] = mone; w[3] = mone;
}

// parallel descending-threshold find on wave 0 (caller syncs around it)
__device__ __forceinline__ void find_thresh(const uint32_t* hist, int nbins, int chunk,
                                            uint32_t need, int* outT, uint32_t* outAbove,
                                            int tid) {
  if (tid < 64) {
    int hi = nbins - 1 - tid * chunk;
    uint32_t csum = 0;
    for (int j = 0; j < chunk; ++j) csum += hist[hi - j];
    uint32_t inc = csum;
#pragma unroll
    for (int off = 1; off < 64; off <<= 1) {
      uint32_t t = (uint32_t)__shfl_up((int)inc, off);
      if (tid >= off) inc += t;
    }
    uint32_t pre = inc - csum;
    if (pre < need && inc >= need) {
      uint32_t cum = pre; int T = hi - chunk + 1;
      for (int j = 0; j < chunk; ++j) {
        int b = hi - j;
        if (cum + hist[b] >= need) { T = b; break; }
        cum += hist[b];
      }
      *outT = T; *outAbove = cum;
    }
  }
}

#define SEL_T 1024
#define NCAND 8192
// exact top-1024 per row: sampled vlo -> single full pass (1 log2/item) -> precise re-key of
// ~4K candidates -> exact 3-level radix select. Ties at exact key -> smallest s.
__global__ void __launch_bounds__(SEL_T) k_select(const float* __restrict__ logw,
                                                  const float* __restrict__ wexp,
                                                  int* __restrict__ idx_sel) {
  const int row = blockIdx.x;
  const int h = row & 15;
  const float* lw = logw + (size_t)h * SZ;
  const f32x4* we4 = (const f32x4*)(wexp + (size_t)h * SZ);
  int* outrow = idx_sel + (size_t)row * NS;
  __shared__ uint32_t ckey[NCAND];   // stage-0 sample keys, then precise candidate keys
  __shared__ int      cidx[NCAND];
  __shared__ uint32_t hist[4096];
  __shared__ int      candA[4096];
  __shared__ int      candB[256];
  __shared__ int      candC[64];
  __shared__ int      ctl[8];        // 0:nsel 1:ncand 2:T 3:CA 4:CB 5:CC 6:above
  __shared__ float    sNA;           // -A = -exp(-vlo)/ln2
  const int tid = threadIdx.x;

  // ---- stage 0: sample every 32nd item (fast keys) -> vlo at sampled rank 128 (~true 4096) ----
#pragma unroll
  for (int j = 0; j < 8; ++j) {
    int k = tid + j * SEL_T;
    int s = k << 5;
    ckey[k] = fkey(lw[s] + gumbel_fast(row, s));
  }
  for (int i = tid; i < 4096; i += SEL_T) hist[i] = 0;
  if (tid < 8) ctl[tid] = 0;
  __syncthreads();
#pragma unroll
  for (int j = 0; j < 8; ++j) atomicAdd(&hist[ckey[tid + j * SEL_T] >> 20], 1u);
  __syncthreads();
  find_thresh(hist, 4096, 64, 128u, &ctl[2], (uint32_t*)&ctl[6], tid);
  __syncthreads();
  const uint32_t T0a = (uint32_t)ctl[2];
  const uint32_t aboveA = (uint32_t)ctl[6];
  for (int i = tid; i < 4096; i += SEL_T) hist[i] = 0;
  __syncthreads();
#pragma unroll
  for (int j = 0; j < 8; ++j) {
    uint32_t k = ckey[tid + j * SEL_T];
    if ((k >> 20) == T0a) atomicAdd(&hist[(k >> 8) & 0xFFFu], 1u);
  }
  __syncthreads();
  find_thresh(hist, 4096, 64, 128u - aboveA, &ctl[2], (uint32_t*)&ctl[6], tid);
  __syncthreads();
  if (tid == 0) {
    uint32_t Tlo = (T0a << 20) | ((uint32_t)ctl[2] << 8);
    float vlo = inv_fkey(Tlo);
    // pass test: lw + g >= vlo  <=>  -log2(u) <= A*exp(lw),  A = exp(-vlo)/ln2
    sNA = -expf(-vlo) * 1.4426950408889634f;
    ctl[1] = 0;
  }
  __syncthreads();
  const float nA = sNA;

  // ---- stage 1: full pass, ILP-4, one log2 per item ----
  for (int g = tid; g < SZ / 4; g += SEL_T) {
    f32x4 w4 = we4[g];
    int s0 = g << 2;
    float l0 = log2u(row, s0);
    float l1 = log2u(row, s0 + 1);
    float l2 = log2u(row, s0 + 2);
    float l3 = log2u(row, s0 + 3);
    // pass iff log2(u) >= -A*wexp
    if (l0 >= nA * w4.x) { int p = atomicAdd(&ctl[1], 1); if (p < NCAND) cidx[p] = s0; }
    if (l1 >= nA * w4.y) { int p = atomicAdd(&ctl[1], 1); if (p < NCAND) cidx[p] = s0 + 1; }
    if (l2 >= nA * w4.z) { int p = atomicAdd(&ctl[1], 1); if (p < NCAND) cidx[p] = s0 + 2; }
    if (l3 >= nA * w4.w) { int p = atomicAdd(&ctl[1], 1); if (p < NCAND) cidx[p] = s0 + 3; }
  }
  __syncthreads();
  const int C = min(ctl[1], NCAND);

  // ---- stage 2: precise re-key + exact 3-level radix select ----
  for (int i = tid; i < 4096; i += SEL_T) hist[i] = 0;
  if (tid == 0) { ctl[0] = 0; ctl[3] = 0; ctl[4] = 0; ctl[5] = 0; }
  __syncthreads();
  for (int ci = tid; ci < C; ci += SEL_T) {
    int s = cidx[ci];
    uint32_t k = fkey(lw[s] + gumbel_precise(row, s));
    ckey[ci] = k;
    atomicAdd(&hist[k >> 20], 1u);
  }
  __syncthreads();
  find_thresh(hist, 4096, 64, (uint32_t)NS, &ctl[2], (uint32_t*)&ctl[6], tid);
  __syncthreads();
  const int T0 = ctl[2];
  for (int ci = tid; ci < C; ci += SEL_T) {
    int b = (int)(ckey[ci] >> 20);
    if (b > T0)       { int p = atomicAdd(&ctl[0], 1); outrow[p] = cidx[ci]; }
    else if (b == T0) { int c = atomicAdd(&ctl[3], 1); if (c < 4096) candA[c] = ci; }
  }
  __syncthreads();
  const int CA = min(ctl[3], 4096);
  for (int i = tid; i < 4096; i += SEL_T) hist[i] = 0;
  __syncthreads();
  for (int i = tid; i < CA; i += SEL_T) atomicAdd(&hist[(ckey[candA[i]] >> 8) & 0xFFFu], 1u);
  __syncthreads();
  find_thresh(hist, 4096, 64, (uint32_t)(NS - ctl[0]), &ctl[2], (uint32_t*)&ctl[6], tid);
  __syncthreads();
  const int T1 = ctl[2];
  for (int i = tid; i < CA; i += SEL_T) {
    int ci = candA[i];
    int mid = (int)((ckey[ci] >> 8) & 0xFFFu);
    if (mid > T1)       { int p = atomicAdd(&ctl[0], 1); outrow[p] = cidx[ci]; }
    else if (mid == T1) { int c = atomicAdd(&ctl[4], 1); if (c < 256) candB[c] = ci; }
  }
  __syncthreads();
  const int CB = min(ctl[4], 256);
  if (tid < 256) hist[tid] = 0;
  __syncthreads();
  for (int i = tid; i < CB; i += SEL_T) atomicAdd(&hist[ckey[candB[i]] & 0xFFu], 1u);
  __syncthreads();
  find_thresh(hist, 256, 4, (uint32_t)(NS - ctl[0]), &ctl[2], (uint32_t*)&ctl[6], tid);
  __syncthreads();
  const int T2 = ctl[2];
  for (int i = tid; i < CB; i += SEL_T) {
    int ci = candB[i];
    int lo = (int)(ckey[ci] & 0xFFu);
    if (lo > T2)       { int p = atomicAdd(&ctl[0], 1); outrow[p] = cidx[ci]; }
    else if (lo == T2) { int c = atomicAdd(&ctl[5], 1); if (c < 64) candC[c] = ci; }
  }
  __syncthreads();
  if (tid == 0) {
    int need = NS - ctl[0];
    int cc = min(ctl[5], 64);
    for (int k = 0; k < need; ++k) {   // exact-key ties: smallest index first
      int best = 0x7fffffff, bi = 0;
      for (int j = 0; j < cc; ++j) { int s = cidx[candC[j]]; if (s < best) { best = s; bi = j; } }
      if (best == 0x7fffffff) best = 0;
      outrow[ctl[0] + k] = best;
      if (cc > 0) cidx[candC[bi]] = 0x7fffffff;
    }
  }
}

#define ATT_T 512
// lane -> (score sj = lane>>3, dim-octet dj = lane&7); float4-pair loads, 3-level shfl reduce
__global__ void __launch_bounds__(ATT_T) k_attn(const float* __restrict__ qin,
    const f32x4* __restrict__ K4, const f32x4* __restrict__ V4,
    const int* __restrict__ idx_sel, float* __restrict__ attn_ws,
    float* __restrict__ lerp_k, float* __restrict__ lerp_v, int* __restrict__ winner) {
  const int row = blockIdx.x;
  const int h = row & 15, b = row >> 4;
  const int tid = threadIdx.x;
  const int lane = tid & 63, wv = tid >> 6;     // 8 waves
  const int sj = lane >> 3, dj = lane & 7;
  __shared__ float sc[NS];
  __shared__ int sel_s[NS];
  __shared__ float red[ATT_T];
  __shared__ f32x4 pk4[8][16], pv4[8][16];
  const int* sel = idx_sel + (size_t)row * NS;
  for (int i = tid; i < NS; i += ATT_T) sel_s[i] = sel[i];
  const f32x4* q4 = (const f32x4*)(qin + (size_t)row * ND);
  f32x4 qa = q4[dj * 2], qb = q4[dj * 2 + 1];
  __syncthreads();
  // phase 1: 8 scores per wave per iter, unroll 2 (4 float4 loads in flight)
  for (int it = 0; it < 16; it += 2) {
    int i1 = it * 64 + wv * 8 + sj;
    int i2 = i1 + 64;
    int x1 = sel_s[i1], x2 = sel_s[i2];
    size_t b1 = ((size_t)x1 * NH + h) * 16 + dj * 2;
    size_t b2 = ((size_t)x2 * NH + h) * 16 + dj * 2;
    f32x4 ka1 = K4[b1], kb1 = K4[b1 + 1];
    f32x4 ka2 = K4[b2], kb2 = K4[b2 + 1];
    float p1 = ka1.x*qa.x + ka1.y*qa.y + ka1.z*qa.z + ka1.w*qa.w
             + kb1.x*qb.x + kb1.y*qb.y + kb1.z*qb.z + kb1.w*qb.w;
    float p2 = ka2.x*qa.x + ka2.y*qa.y + ka2.z*qa.z + ka2.w*qa.w
             + kb2.x*qb.x + kb2.y*qb.y + kb2.z*qb.z + kb2.w*qb.w;
#pragma unroll
    for (int off = 1; off < 8; off <<= 1) { p1 += __shfl_xor(p1, off); p2 += __shfl_xor(p2, off); }
    if (dj == 0) { sc[i1] = p1 * 0.125f; sc[i2] = p2 * 0.125f; }
  }
  __syncthreads();
  // softmax over 1024 scores, 2 per thread
  float v1 = sc[tid], v2 = sc[tid + 512];
  red[tid] = fmaxf(v1, v2); __syncthreads();
  for (int s = 256; s; s >>= 1) { if (tid < s) red[tid] = fmaxf(red[tid], red[tid + s]); __syncthreads(); }
  float m = red[0]; __syncthreads();
  float e1 = expf(v1 - m), e2 = expf(v2 - m);
  red[tid] = e1 + e2; __syncthreads();
  for (int s = 256; s; s >>= 1) { if (tid < s) red[tid] += red[tid + s]; __syncthreads(); }
  float inv = 1.0f / red[0];
  float a1 = e1 * inv, a2 = e2 * inv;
  sc[tid] = a1; sc[tid + 512] = a2;
  attn_ws[(size_t)row * NS + tid] = a1;
  attn_ws[(size_t)row * NS + tid + 512] = a2;
  __syncthreads();
  // phase 2: lerp accumulation (8 float4 loads in flight via unroll 2)
  f32x4 AK = 0.f, BK = 0.f, AV = 0.f, BV = 0.f;
  for (int it = 0; it < 16; it += 2) {
    int i1 = it * 64 + wv * 8 + sj;
    int i2 = i1 + 64;
    int x1 = sel_s[i1], x2 = sel_s[i2];
    float c1 = sc[i1], c2 = sc[i2];
    size_t b1 = ((size_t)x1 * NH + h) * 16 + dj * 2;
    size_t b2 = ((size_t)x2 * NH + h) * 16 + dj * 2;
    f32x4 k1a = K4[b1], k1b = K4[b1 + 1], v1a = V4[b1], v1b = V4[b1 + 1];
    f32x4 k2a = K4[b2], k2b = K4[b2 + 1], v2a = V4[b2], v2b = V4[b2 + 1];
    AK += c1 * k1a + c2 * k2a; BK += c1 * k1b + c2 * k2b;
    AV += c1 * v1a + c2 * v2a; BV += c1 * v1b + c2 * v2b;
  }
#pragma unroll
  for (int off = 8; off < 64; off <<= 1) {
    AK.x += __shfl_xor(AK.x, off); AK.y += __shfl_xor(AK.y, off);
    AK.z += __shfl_xor(AK.z, off); AK.w += __shfl_xor(AK.w, off);
    BK.x += __shfl_xor(BK.x, off); BK.y += __shfl_xor(BK.y, off);
    BK.z += __shfl_xor(BK.z, off); BK.w += __shfl_xor(BK.w, off);
    AV.x += __shfl_xor(AV.x, off); AV.y += __shfl_xor(AV.y, off);
    AV.z += __shfl_xor(AV.z, off); AV.w += __shfl_xor(AV.w, off);
    BV.x += __shfl_xor(BV.x, off); BV.y += __shfl_xor(BV.y, off);
    BV.z += __shfl_xor(BV.z, off); BV.w += __shfl_xor(BV.w, off);
  }
  if (sj == 0) {
    pk4[wv][dj * 2] = AK; pk4[wv][dj * 2 + 1] = BK;
    pv4[wv][dj * 2] = AV; pv4[wv][dj * 2 + 1] = BV;
  }
  __syncthreads();
  if (tid < 64) {
    float lk = 0.f, lv = 0.f;
    const float* pkf = (const float*)pk4;
    const float* pvf = (const float*)pv4;
#pragma unroll
    for (int ww = 0; ww < 8; ++ww) { lk += pkf[ww * 64 + tid]; lv += pvf[ww * 64 + tid]; }
    lerp_k[(size_t)row * ND + tid] = lk;
    lerp_v[(size_t)row * ND + tid] = lv;
  }
  // winner map: last-write-wins over b == max b per (idx,h)
  for (int i = tid; i < NS; i += ATT_T) atomicMax(&winner[(size_t)sel_s[i] * NH + h], b);
}

// winning slots: record attn weight and fix outL
__global__ void k_mark(const int* __restrict__ idx_sel, const float* __restrict__ attn_ws,
                       const int* __restrict__ winner, const float* __restrict__ Lst,
                       float* __restrict__ wa, float* __restrict__ outL) {
  int t = blockIdx.x * 256 + threadIdx.x;   // NROW*NS threads exactly
  int row = t >> 10, h = row & 15, b = row >> 4;
  int idx = idx_sel[t];
  size_t slot = (size_t)idx * NH + h;
  if (winner[slot] == b) {
    float a = attn_ws[t];
    wa[slot] = a;
    outL[slot] = 0.99f * Lst[slot] + a;
  }
}

// pure K/V streaming copy-or-blend; compile-time 32 iters per thread
__global__ void __launch_bounds__(256) k_emit(const f32x4* __restrict__ K4,
    const f32x4* __restrict__ V4, const int* __restrict__ winner,
    const float* __restrict__ wa, const f32x4* __restrict__ LK4,
    const f32x4* __restrict__ LV4, f32x4* __restrict__ oK4, f32x4* __restrict__ oV4) {
  const long tid0 = (long)blockIdx.x * 256 + threadIdx.x;
  const long stride = 8192L * 256;
#pragma unroll 2
  for (int r = 0; r < 32; ++r) {
    long i = tid0 + (long)r * stride;
    int slot = (int)(i >> 4);
    int w = winner[slot];
    f32x4 kv = __builtin_nontemporal_load(&K4[i]);
    f32x4 vv = __builtin_nontemporal_load(&V4[i]);
    if (w >= 0) {
      float a = wa[slot];
      int rr = (w << 4) | (slot & 15);
      f32x4 lk = LK4[((long)rr << 4) + (i & 15)];
      f32x4 lv = LV4[((long)rr << 4) + (i & 15)];
      float o = 1.0f - a;
      kv = o * kv + a * lk;
      vv = o * vv + a * lv;
    }
    __builtin_nontemporal_store(kv, &oK4[i]);
    __builtin_nontemporal_store(vv, &oV4[i]);
  }
}

extern "C" void kernel_launch(void* const* d_in, const int* in_sizes, int n_in,
                              void* d_out, int out_size, void* d_ws, size_t ws_size,
                              hipStream_t stream) {
  const float* q   = (const float*)d_in[0];
  const float* Kst = (const float*)d_in[1];
  const float* Vst = (const float*)d_in[2];
  const float* Lst = (const float*)d_in[3];

  float* out    = (float*)d_out;
  float* out_lk = out;                        // (B,H,D)
  float* out_lv = out + 32768;
  float* outK   = out + 65536;                // (SIZE,H,D)
  float* outV   = outK + 268435456;
  float* outL   = outV + 268435456;           // (SIZE,H)

  char* ws = (char*)d_ws;
  float* logw   = (float*)ws;                         // 16 MB (H,SIZE)
  float* wexp   = (float*)(ws + (16ull << 20));       // 16 MB (H,SIZE)
  int*   idxsel = (int*)(ws + (32ull << 20));         //  2 MB (NROW,NS)
  float* attn   = (float*)(ws + (34ull << 20));       //  2 MB
  int*   winner = (int*)(ws + (36ull << 20));         // 16 MB (SIZE,H)
  float* wa     = (float*)(ws + (52ull << 20));       // 16 MB (SIZE,H)

  k_logw<<<SZ / 256, 256, 0, stream>>>(Lst, logw, wexp, outL, winner);
  k_select<<<NROW, SEL_T, 0, stream>>>(logw, wexp, idxsel);
  k_attn<<<NROW, ATT_T, 0, stream>>>(q, (const f32x4*)Kst, (const f32x4*)Vst,
                                     idxsel, attn, out_lk, out_lv, winner);
  k_mark<<<NROW * NS / 256, 256, 0, stream>>>(idxsel, attn, winner, Lst, wa, outL);
  k_emit<<<8192, 256, 0, stream>>>((const f32x4*)Kst, (const f32x4*)Vst, winner, wa,
                                   (const f32x4*)out_lk, (const f32x4*)out_lv,
                                   (f32x4*)outK, (f32x4*)outV);
}